// Round 1
// baseline (44.662 us; speedup 1.0000x reference)
//
#include <hip/hip_runtime.h>
#include <hip/hip_bf16.h>

// Shapes (from reference setup):
//   x:        (32, 512, 384) float32
//   duration: (32, 512)      int32, values in [0,16)
//   max_len = 4096
// Outputs (concatenated flat in d_out, all read back as float32):
//   out:   (32, 4096, 384) float32   -> d_out[0 .. 50331647]
//   total: (32,)                     -> d_out[50331648 .. 50331679] (float values)

#define B      32
#define S      512          // source rows per batch
#define T      4096         // max_len
#define D      384          // feature dim (96 float4)
#define D4     96
#define TILE_T 64           // t-rows per block in gather kernel

// ---------------------------------------------------------------------------
// Kernel 1: per-batch inclusive scan of duration -> cs (ws), total -> d_out tail
// ---------------------------------------------------------------------------
__global__ __launch_bounds__(S) void lr_scan_kernel(
    const int* __restrict__ duration,   // (B,S)
    int* __restrict__ cs,               // (B,S) workspace
    float* __restrict__ total_out)      // (B,) at d_out tail
{
    const int b   = blockIdx.x;
    const int tid = threadIdx.x;        // 0..511

    __shared__ int s[S];

    int d = duration[b * S + tid];
    d = max(d, 0);
    s[tid] = d;
    __syncthreads();

    // Hillis-Steele inclusive scan (read -> barrier -> write -> barrier)
    #pragma unroll
    for (int off = 1; off < S; off <<= 1) {
        int v = (tid >= off) ? s[tid - off] : 0;
        __syncthreads();
        s[tid] += v;
        __syncthreads();
    }

    cs[b * S + tid] = s[tid];
    if (tid == 0) {
        total_out[b] = (float)s[S - 1];
    }
}

// ---------------------------------------------------------------------------
// Kernel 2: gather-copy. Block = (batch, 64-row t-tile).
// ---------------------------------------------------------------------------
__global__ __launch_bounds__(256) void lr_gather_kernel(
    const float4* __restrict__ x,       // (B, S, D4)
    const int*    __restrict__ cs,      // (B, S)
    float4*       __restrict__ out)     // (B, T, D4)
{
    const int blk = blockIdx.x;
    const int b   = blk >> 6;                 // T/TILE_T = 64 blocks per batch
    const int t0  = (blk & 63) * TILE_T;
    const int tid = threadIdx.x;

    __shared__ int s_cs[S];
    __shared__ int s_idx[TILE_T];

    s_cs[tid]       = cs[b * S + tid];
    s_cs[tid + 256] = cs[b * S + tid + 256];
    __syncthreads();

    const int total = s_cs[S - 1];

    if (tid < TILE_T) {
        const int t = t0 + tid;
        int idx = -1;                          // -1 => write zeros
        if (t < total) {
            // branchless upper_bound: lo = #elements cs[j] <= t
            int lo = 0;
            #pragma unroll
            for (int step = 256; step > 0; step >>= 1) {
                int mid = lo + step;
                if (mid <= S && s_cs[mid - 1] <= t) lo = mid;
            }
            idx = min(lo, S - 1);
        }
        s_idx[tid] = idx;
    }
    __syncthreads();

    const float4* xb = x   + (size_t)b * S * D4;
    float4*       ob = out + ((size_t)b * T + t0) * D4;

    // 64 rows x 96 float4 = 6144 float4 per block; 24 iters per thread.
    #pragma unroll 4
    for (int e = tid; e < TILE_T * D4; e += 256) {
        const int r = e / D4;                 // constant div -> magic mul
        const int c = e - r * D4;
        const int idx = s_idx[r];
        float4 v;
        if (idx < 0) {
            v = make_float4(0.f, 0.f, 0.f, 0.f);
        } else {
            v = xb[idx * D4 + c];
        }
        ob[r * D4 + c] = v;
    }
}

// ---------------------------------------------------------------------------
extern "C" void kernel_launch(void* const* d_in, const int* in_sizes, int n_in,
                              void* d_out, int out_size, void* d_ws, size_t ws_size,
                              hipStream_t stream) {
    const float* x        = (const float*)d_in[0];
    const int*   duration = (const int*)d_in[1];
    // d_in[2] = max_len scalar (=4096), compile-time constant here.

    float* out      = (float*)d_out;
    float* total_of = out + (size_t)B * T * D;   // tail of d_out
    int*   cs       = (int*)d_ws;                // 32*512*4 = 64 KiB

    lr_scan_kernel<<<B, S, 0, stream>>>(duration, cs, total_of);

    const int nblocks = B * (T / TILE_T);        // 2048
    lr_gather_kernel<<<nblocks, 256, 0, stream>>>(
        (const float4*)x, cs, (float4*)out);
}

// Round 2
// 40.691 us; speedup vs baseline: 1.0976x; 1.0976x over previous
//
#include <hip/hip_runtime.h>
#include <hip/hip_bf16.h>

// Shapes (from reference setup):
//   x:        (32, 512, 384) float32
//   duration: (32, 512)      int32, values in [0,16)
//   max_len = 4096
// Outputs (concatenated flat in d_out, all read back as float32):
//   out:   (32, 4096, 384) float32   -> d_out[0 .. 50331647]
//   total: (32,)                     -> d_out[50331648 .. 50331679] (float values)

#define B      32
#define S      512          // source rows per batch
#define T      4096         // max_len
#define D      384          // feature dim (96 float4)
#define D4     96
#define TILE_T 64           // t-rows per block

// ---------------------------------------------------------------------------
// Fused kernel: each block re-derives the per-batch cumsum from `duration`
// in LDS (cheap: 512 ints, 8-round scan), then binary-searches its 64 t-rows
// and streams the gathered float4 rows. No inter-kernel dependency.
// Block = (batch, 64-row t-tile); grid = 32 * 64 = 2048 blocks.
// ---------------------------------------------------------------------------
__global__ __launch_bounds__(256) void lr_fused_kernel(
    const float4* __restrict__ x,        // (B, S, D4)
    const int*    __restrict__ duration, // (B, S)
    float4*       __restrict__ out,      // (B, T, D4)
    float*        __restrict__ total_out)// (B,) at d_out tail
{
    const int blk = blockIdx.x;
    const int b   = blk >> 6;                 // 64 tiles per batch
    const int t0  = (blk & 63) * TILE_T;
    const int tid = threadIdx.x;              // 0..255

    __shared__ int s_cs[S];                   // inclusive cumsum
    __shared__ int s_p[256];                  // pair partial sums
    __shared__ int s_idx[TILE_T];

    // --- local scan of durations (2 elements per thread) ---
    const int2 d2 = ((const int2*)(duration + b * S))[tid];
    const int a0 = max(d2.x, 0);
    const int a1 = max(d2.y, 0);
    s_p[tid] = a0 + a1;
    __syncthreads();

    // Hillis-Steele inclusive scan over the 256 pair sums
    #pragma unroll
    for (int off = 1; off < 256; off <<= 1) {
        int v = (tid >= off) ? s_p[tid - off] : 0;
        __syncthreads();
        s_p[tid] += v;
        __syncthreads();
    }

    const int P = s_p[tid];                   // inclusive sum through pair tid
    s_cs[2 * tid]     = P - a1;
    s_cs[2 * tid + 1] = P;
    __syncthreads();

    const int total = s_cs[S - 1];

    if (t0 == 0 && tid == 0) {
        total_out[b] = (float)total;
    }

    // --- per-row source index via branchless upper_bound ---
    if (tid < TILE_T) {
        const int t = t0 + tid;
        int idx = -1;                          // -1 => write zeros
        if (t < total) {
            int lo = 0;                        // lo = #elements cs[j] <= t
            #pragma unroll
            for (int step = 256; step > 0; step >>= 1) {
                int mid = lo + step;
                if (mid <= S && s_cs[mid - 1] <= t) lo = mid;
            }
            idx = min(lo, S - 1);
        }
        s_idx[tid] = idx;
    }
    __syncthreads();

    // --- gather-copy: 64 rows x 96 float4 = 6144 float4 per block ---
    const float4* xb = x   + (size_t)b * S * D4;
    float4*       ob = out + ((size_t)b * T + t0) * D4;

    #pragma unroll 4
    for (int e = tid; e < TILE_T * D4; e += 256) {
        const int r = e / D4;                 // constant div -> magic mul
        const int c = e - r * D4;
        const int idx = s_idx[r];
        float4 v;
        if (idx < 0) {
            v = make_float4(0.f, 0.f, 0.f, 0.f);
        } else {
            v = xb[idx * D4 + c];
        }
        ob[r * D4 + c] = v;
    }
}

// ---------------------------------------------------------------------------
extern "C" void kernel_launch(void* const* d_in, const int* in_sizes, int n_in,
                              void* d_out, int out_size, void* d_ws, size_t ws_size,
                              hipStream_t stream) {
    const float* x        = (const float*)d_in[0];
    const int*   duration = (const int*)d_in[1];
    // d_in[2] = max_len scalar (=4096), compile-time constant here.

    float* out      = (float*)d_out;
    float* total_of = out + (size_t)B * T * D;   // tail of d_out

    const int nblocks = B * (T / TILE_T);        // 2048
    lr_fused_kernel<<<nblocks, 256, 0, stream>>>(
        (const float4*)x, duration, (float4*)out, total_of);
}